// Round 1
// baseline (1184.815 us; speedup 1.0000x reference)
//
#include <hip/hip_runtime.h>
#include <hip/hip_bf16.h>

#define BSZ 16
#define LEN 2048
#define CH  2048
#define DIN 96
#define NST 16
#define RNK 6
#define NROW (BSZ*LEN)   // 32768

typedef __attribute__((ext_vector_type(4))) float f32x4;
typedef __attribute__((ext_vector_type(8))) short bf16x8;

static __device__ __forceinline__ unsigned short f2bf(float f) {
  union { float f; unsigned u; } v; v.f = f;
  unsigned r = v.u + 0x7fff + ((v.u >> 16) & 1);   // RNE
  return (unsigned short)(r >> 16);
}

static __device__ __forceinline__ f32x4 mfma16(bf16x8 a, bf16x8 b, f32x4 c) {
  return __builtin_amdgcn_mfma_f32_16x16x32_bf16(a, b, c, 0, 0, 0);
}

// ---------------- K0: prep — convert weights to bf16, fold dtW@xW[:6] ----------------
__global__ void k_prep(const float* __restrict__ inW, const float* __restrict__ outW,
                       const float* __restrict__ xW, const float* __restrict__ dtW,
                       unsigned short* __restrict__ inWb, unsigned short* __restrict__ outWb,
                       float* __restrict__ M1t, float* __restrict__ xBC) {
  int i = blockIdx.x * 256 + threadIdx.x;
  if (i < DIN*CH)  inWb[i]  = f2bf(inW[i]);
  if (i < CH*DIN)  outWb[i] = f2bf(outW[i]);
  if (i < DIN*DIN) {                 // M1t[c*96+d] = sum_r dtW[d,r]*xW[r,c]
    int c = i / DIN, d = i - c*DIN;
    float s = 0.f;
    #pragma unroll
    for (int r = 0; r < RNK; ++r) s += dtW[d*RNK + r] * xW[r*DIN + c];
    M1t[i] = s;
  }
  if (i < DIN*32) {                  // xBC[c*32+n] = xW[6+n, c]  (transposed B/C proj)
    int c = i / 32, n = i - c*32;
    xBC[i] = xW[(RNK + n)*DIN + c];
  }
}

// ---------------- K2: fused LN stats + LN apply + in_proj (bf16 MFMA) ----------------
#define K2_ROWS 64
#define K2_KC   64
#define K2_LDA  72    // padded: 144B row stride, 16B aligned, bank-spread

__launch_bounds__(256)
__global__ void k_ln_inproj(const float* __restrict__ feat,
                            const float* __restrict__ lnw, const float* __restrict__ lnb,
                            const unsigned short* __restrict__ Wb,
                            float* __restrict__ xin) {
  __shared__ unsigned short A_lds[K2_ROWS][K2_LDA];
  __shared__ unsigned short W_lds[DIN][K2_LDA];
  __shared__ float mu_s[K2_ROWS], rs_s[K2_ROWS];

  const int tid  = threadIdx.x;
  const int lane = tid & 63;
  const int w    = tid >> 6;
  const int r0   = blockIdx.x * K2_ROWS;

  // per-row LN stats: wave w reduces rows w*16..w*16+15 (feat read lands in L2 for K-loop)
  for (int rr = 0; rr < 16; ++rr) {
    int row = w*16 + rr;
    const float4* p = (const float4*)(feat + (size_t)(r0 + row) * CH);
    float s = 0.f, q = 0.f;
    #pragma unroll
    for (int i = 0; i < 8; ++i) {
      float4 v = p[lane + 64*i];
      s += v.x + v.y + v.z + v.w;
      q += v.x*v.x + v.y*v.y + v.z*v.z + v.w*v.w;
    }
    #pragma unroll
    for (int off = 32; off; off >>= 1) { s += __shfl_xor(s, off); q += __shfl_xor(q, off); }
    if (lane == 0) {
      float mu = s * (1.f/CH);
      float var = q * (1.f/CH) - mu*mu;
      mu_s[row] = mu; rs_s[row] = rsqrtf(var + 1e-5f);
    }
  }
  __syncthreads();

  f32x4 acc[6];
  #pragma unroll
  for (int i = 0; i < 6; ++i) acc[i] = (f32x4){0.f, 0.f, 0.f, 0.f};

  for (int kc = 0; kc < CH; kc += K2_KC) {
    __syncthreads();
    // stage A: 64 rows x 64 k, LN applied, fp32 -> bf16
    #pragma unroll
    for (int i = 0; i < 4; ++i) {
      int j = tid + 256*i;
      int row = j >> 4, kq = j & 15;
      float4 v  = *(const float4*)(feat + (size_t)(r0 + row)*CH + kc + kq*4);
      float4 wv = *(const float4*)(lnw + kc + kq*4);
      float4 bv = *(const float4*)(lnb + kc + kq*4);
      float mu = mu_s[row], rs = rs_s[row];
      ushort4 pk = make_ushort4(f2bf((v.x - mu)*rs*wv.x + bv.x),
                                f2bf((v.y - mu)*rs*wv.y + bv.y),
                                f2bf((v.z - mu)*rs*wv.z + bv.z),
                                f2bf((v.w - mu)*rs*wv.w + bv.w));
      *(ushort4*)&A_lds[row][kq*4] = pk;
    }
    // stage W (B^T layout, pre-converted bf16): 96 rows x 64 k
    #pragma unroll
    for (int i = 0; i < 6; ++i) {
      int j = tid + 256*i;
      int row = j >> 4, kq = j & 15;
      ushort4 pk = *(const ushort4*)(Wb + (size_t)row*CH + kc + kq*4);
      *(ushort4*)&W_lds[row][kq*4] = pk;
    }
    __syncthreads();
    #pragma unroll
    for (int kt = 0; kt < 2; ++kt) {
      int krd = kt*32 + (lane >> 4)*8;
      bf16x8 af = *(const bf16x8*)&A_lds[w*16 + (lane & 15)][krd];
      #pragma unroll
      for (int ct = 0; ct < 6; ++ct) {
        bf16x8 bfr = *(const bf16x8*)&W_lds[ct*16 + (lane & 15)][krd];
        acc[ct] = mfma16(af, bfr, acc[ct]);
      }
    }
  }
  // epilogue: C/D layout col=lane&15, row=(lane>>4)*4+reg
  int rloc = w*16 + (lane >> 4)*4;
  int cl = lane & 15;
  #pragma unroll
  for (int ct = 0; ct < 6; ++ct)
    #pragma unroll
    for (int i = 0; i < 4; ++i)
      xin[(size_t)(r0 + rloc + i)*DIN + ct*16 + cl] = acc[ct][i];
}

// ---------------- K3: depthwise conv3 + silu + x_proj/dt_proj ----------------
#define K3_R 8
__launch_bounds__(128)
__global__ void k_conv_proj(const float* __restrict__ xin,
                            const float* __restrict__ cw, const float* __restrict__ cb,
                            const float* __restrict__ xBC, const float* __restrict__ M1t,
                            const float* __restrict__ dtb,
                            float* __restrict__ ug, float* __restrict__ dg,
                            float* __restrict__ Bg, float* __restrict__ Cg) {
  __shared__ float su[K3_R][DIN];
  const int b  = blockIdx.y;
  const int l0 = blockIdx.x * K3_R;
  const int t  = threadIdx.x;

  if (t < DIN) {
    float x[K3_R + 2];
    #pragma unroll
    for (int i = 0; i < K3_R + 2; ++i) {
      int li = l0 - 1 + i;
      x[i] = (li >= 0 && li < LEN) ? xin[((size_t)b*LEN + li)*DIN + t] : 0.f;
    }
    float w0 = cw[t*3], w1 = cw[t*3+1], w2 = cw[t*3+2], bb = cb[t];
    #pragma unroll
    for (int r = 0; r < K3_R; ++r) {
      float c = w0*x[r] + w1*x[r+1] + w2*x[r+2] + bb;
      float uu = c / (1.f + __expf(-c));        // silu
      su[r][t] = uu;
      ug[((size_t)b*LEN + l0 + r)*DIN + t] = uu;
    }
  }
  __syncthreads();
  if (t < DIN) {
    float z[K3_R];
    #pragma unroll
    for (int r = 0; r < K3_R; ++r) z[r] = dtb[t];
    for (int c = 0; c < DIN; ++c) {
      float m = M1t[c*DIN + t];                 // coalesced
      #pragma unroll
      for (int r = 0; r < K3_R; ++r) z[r] += su[r][c] * m;
    }
    #pragma unroll
    for (int r = 0; r < K3_R; ++r) {
      float zz = z[r];
      float sp = (zz > 20.f) ? zz : log1pf(__expf(zz));
      dg[((size_t)b*LEN + l0 + r)*DIN + t] = 0.001f * sp;
    }
  } else if (t < DIN + 32) {
    int n = t - DIN;
    float s[K3_R];
    #pragma unroll
    for (int r = 0; r < K3_R; ++r) s[r] = 0.f;
    for (int c = 0; c < DIN; ++c) {
      float wv = xBC[c*32 + n];                 // coalesced
      #pragma unroll
      for (int r = 0; r < K3_R; ++r) s[r] += su[r][c] * wv;
    }
    #pragma unroll
    for (int r = 0; r < K3_R; ++r) {
      size_t row = (size_t)b*LEN + l0 + r;
      if (n < 16) Bg[row*NST + n]        = s[r];
      else        Cg[row*NST + (n - 16)] = s[r];
    }
  }
}

// ---------------- K4: selective scan — lane per (b,d,n), fma-only dep chain ----------------
__launch_bounds__(64)
__global__ void k_scan(const float* __restrict__ dg, const float* __restrict__ ug,
                       const float* __restrict__ Bg, const float* __restrict__ Cg,
                       const float* __restrict__ Alog, const float* __restrict__ Dp,
                       unsigned short* __restrict__ yb) {
  const int lane = threadIdx.x & 63;
  const int wid  = blockIdx.x;          // 384 waves, 4 (b,d) pairs each
  const int p = lane >> 4, n = lane & 15;
  const int pair = wid*4 + p;           // 0..1535
  const int b = pair / DIN;
  const int d = pair - b*DIN;
  const float An = -__expf(Alog[d*NST + n]);
  const float Dd = Dp[d];
  const float* dptr = dg + (size_t)b*LEN*DIN + d;
  const float* uptr = ug + (size_t)b*LEN*DIN + d;
  const float* bptr = Bg + (size_t)b*LEN*NST + n;
  const float* cptr = Cg + (size_t)b*LEN*NST + n;
  unsigned short* yptr = yb + (size_t)b*LEN*DIN + d;

  float s = 0.f;
  #pragma unroll 4
  for (int t = 0; t < LEN; ++t) {
    float dl = dptr[(size_t)t*DIN];
    float uu = uptr[(size_t)t*DIN];
    float bp = bptr[(size_t)t*NST];
    float cp = cptr[(size_t)t*NST];
    float dA  = __expf(dl * An);
    s = fmaf(dA, s, dl * bp * uu);
    float py = s * cp;
    #pragma unroll
    for (int off = 8; off; off >>= 1) py += __shfl_xor(py, off);
    if (n == 0) yptr[(size_t)t*DIN] = f2bf(py + uu * Dd);
  }
}

// ---------------- K5: out_proj (bf16 MFMA) + residual ----------------
#define K6_MR 128
#define K6_NC 128
#define K6_LD 104   // 208B row stride, 16B aligned

__launch_bounds__(256)
__global__ void k_outproj(const unsigned short* __restrict__ yb,
                          const unsigned short* __restrict__ Wb,  // (2048 x 96) bf16
                          const float* __restrict__ resid,
                          float* __restrict__ out) {
  __shared__ unsigned short Y_lds[K6_MR][K6_LD];
  __shared__ unsigned short W_lds[K6_NC][K6_LD];
  const int tid  = threadIdx.x;
  const int lane = tid & 63;
  const int w    = tid >> 6;
  const int r0   = blockIdx.y * K6_MR;
  const int c0   = blockIdx.x * K6_NC;

  #pragma unroll
  for (int i = 0; i < 12; ++i) {
    int j = tid + 256*i;
    int row = j / 24, q = j - row*24;
    *(ushort4*)&Y_lds[row][q*4] = *(const ushort4*)(yb + (size_t)(r0 + row)*DIN + q*4);
  }
  #pragma unroll
  for (int i = 0; i < 12; ++i) {
    int j = tid + 256*i;
    int row = j / 24, q = j - row*24;
    *(ushort4*)&W_lds[row][q*4] = *(const ushort4*)(Wb + (size_t)(c0 + row)*DIN + q*4);
  }
  __syncthreads();

  f32x4 acc[2][8];
  #pragma unroll
  for (int i = 0; i < 2; ++i)
    #pragma unroll
    for (int j = 0; j < 8; ++j) acc[i][j] = (f32x4){0.f, 0.f, 0.f, 0.f};

  #pragma unroll
  for (int kt = 0; kt < 3; ++kt) {     // K = 96 = 3 x 32
    int krd = kt*32 + (lane >> 4)*8;
    bf16x8 a0 = *(const bf16x8*)&Y_lds[w*32 +      (lane & 15)][krd];
    bf16x8 a1 = *(const bf16x8*)&Y_lds[w*32 + 16 + (lane & 15)][krd];
    #pragma unroll
    for (int ct = 0; ct < 8; ++ct) {
      bf16x8 bfr = *(const bf16x8*)&W_lds[ct*16 + (lane & 15)][krd];
      acc[0][ct] = mfma16(a0, bfr, acc[0][ct]);
      acc[1][ct] = mfma16(a1, bfr, acc[1][ct]);
    }
  }

  const int cl = lane & 15;
  const int rl = (lane >> 4)*4;
  #pragma unroll
  for (int i = 0; i < 2; ++i)
    #pragma unroll
    for (int ct = 0; ct < 8; ++ct)
      #pragma unroll
      for (int r = 0; r < 4; ++r) {
        size_t row = (size_t)(r0 + w*32 + i*16 + rl + r);
        size_t col = (size_t)(c0 + ct*16 + cl);
        size_t idx = row*CH + col;
        out[idx] = acc[i][ct][r] + resid[idx];
      }
}

extern "C" void kernel_launch(void* const* d_in, const int* in_sizes, int n_in,
                              void* d_out, int out_size, void* d_ws, size_t ws_size,
                              hipStream_t stream) {
  const float* feat = (const float*)d_in[0];
  const float* lnw  = (const float*)d_in[1];
  const float* lnb  = (const float*)d_in[2];
  const float* inW  = (const float*)d_in[3];
  const float* cw   = (const float*)d_in[4];
  const float* cb   = (const float*)d_in[5];
  const float* xW   = (const float*)d_in[6];
  const float* dtW  = (const float*)d_in[7];
  const float* dtb  = (const float*)d_in[8];
  const float* Alog = (const float*)d_in[9];
  const float* Dp   = (const float*)d_in[10];
  const float* outW = (const float*)d_in[11];
  float* out = (float*)d_out;

  char* ws = (char*)d_ws;
  size_t off = 0;
  auto alloc = [&](size_t bytes) { void* p = ws + off; off += (bytes + 255) & ~255ull; return p; };
  unsigned short* inWb  = (unsigned short*)alloc((size_t)DIN*CH*2);
  unsigned short* outWb = (unsigned short*)alloc((size_t)CH*DIN*2);
  float* M1t = (float*)alloc((size_t)DIN*DIN*4);
  float* xBC = (float*)alloc((size_t)DIN*32*4);
  float* xin = (float*)alloc((size_t)NROW*DIN*4);
  float* ug  = (float*)alloc((size_t)NROW*DIN*4);
  float* dg  = (float*)alloc((size_t)NROW*DIN*4);
  float* Bg  = (float*)alloc((size_t)NROW*NST*4);
  float* Cg  = (float*)alloc((size_t)NROW*NST*4);
  unsigned short* yb = (unsigned short*)alloc((size_t)NROW*DIN*2);
  // total ~49 MB of d_ws

  hipLaunchKernelGGL(k_prep, dim3((DIN*CH + 255)/256), dim3(256), 0, stream,
                     inW, outW, xW, dtW, inWb, outWb, M1t, xBC);
  hipLaunchKernelGGL(k_ln_inproj, dim3(NROW/K2_ROWS), dim3(256), 0, stream,
                     feat, lnw, lnb, inWb, xin);
  hipLaunchKernelGGL(k_conv_proj, dim3(LEN/K3_R, BSZ), dim3(128), 0, stream,
                     xin, cw, cb, xBC, M1t, dtb, ug, dg, Bg, Cg);
  hipLaunchKernelGGL(k_scan, dim3(384), dim3(64), 0, stream,
                     dg, ug, Bg, Cg, Alog, Dp, yb);
  hipLaunchKernelGGL(k_outproj, dim3(CH/K6_NC, NROW/K6_MR), dim3(256), 0, stream,
                     yb, outWb, feat, out);
}

// Round 2
// 479.281 us; speedup vs baseline: 2.4721x; 2.4721x over previous
//
#include <hip/hip_runtime.h>
#include <hip/hip_bf16.h>

#define BSZ 16
#define LEN 2048
#define CH  2048
#define DIN 96
#define NST 16
#define RNK 6
#define NROW (BSZ*LEN)   // 32768
#define TCH  256
#define NCHK (LEN/TCH)   // 8
#define NPAIR (BSZ*DIN)  // 1536

typedef __attribute__((ext_vector_type(4))) float f32x4;
typedef __attribute__((ext_vector_type(8))) short bf16x8;

static __device__ __forceinline__ unsigned short f2bf(float f) {
  union { float f; unsigned u; } v; v.f = f;
  unsigned r = v.u + 0x7fff + ((v.u >> 16) & 1);   // RNE
  return (unsigned short)(r >> 16);
}

static __device__ __forceinline__ f32x4 mfma16(bf16x8 a, bf16x8 b, f32x4 c) {
  return __builtin_amdgcn_mfma_f32_16x16x32_bf16(a, b, c, 0, 0, 0);
}

// ---------------- K0: prep — convert weights to bf16, fold dtW@xW[:6] ----------------
__global__ void k_prep(const float* __restrict__ inW, const float* __restrict__ outW,
                       const float* __restrict__ xW, const float* __restrict__ dtW,
                       unsigned short* __restrict__ inWb, unsigned short* __restrict__ outWb,
                       float* __restrict__ M1t, float* __restrict__ xBC) {
  int i = blockIdx.x * 256 + threadIdx.x;
  if (i < DIN*CH)  inWb[i]  = f2bf(inW[i]);
  if (i < CH*DIN)  outWb[i] = f2bf(outW[i]);
  if (i < DIN*DIN) {                 // M1t[c*96+d] = sum_r dtW[d,r]*xW[r,c]
    int c = i / DIN, d = i - c*DIN;
    float s = 0.f;
    #pragma unroll
    for (int r = 0; r < RNK; ++r) s += dtW[d*RNK + r] * xW[r*DIN + c];
    M1t[i] = s;
  }
  if (i < DIN*32) {                  // xBC[c*32+n] = xW[6+n, c]  (transposed B/C proj)
    int c = i / 32, n = i - c*32;
    xBC[i] = xW[(RNK + n)*DIN + c];
  }
}

// ---------------- K2: fused LN stats + LN apply + in_proj (bf16 MFMA) ----------------
#define K2_ROWS 64
#define K2_KC   64
#define K2_LDA  72    // padded: 144B row stride, 16B aligned, bank-spread

__launch_bounds__(256)
__global__ void k_ln_inproj(const float* __restrict__ feat,
                            const float* __restrict__ lnw, const float* __restrict__ lnb,
                            const unsigned short* __restrict__ Wb,
                            float* __restrict__ xin) {
  __shared__ unsigned short A_lds[K2_ROWS][K2_LDA];
  __shared__ unsigned short W_lds[DIN][K2_LDA];
  __shared__ float mu_s[K2_ROWS], rs_s[K2_ROWS];

  const int tid  = threadIdx.x;
  const int lane = tid & 63;
  const int w    = tid >> 6;
  const int r0   = blockIdx.x * K2_ROWS;

  // per-row LN stats: wave w reduces rows w*16..w*16+15 (feat read lands in L2 for K-loop)
  for (int rr = 0; rr < 16; ++rr) {
    int row = w*16 + rr;
    const float4* p = (const float4*)(feat + (size_t)(r0 + row) * CH);
    float s = 0.f, q = 0.f;
    #pragma unroll
    for (int i = 0; i < 8; ++i) {
      float4 v = p[lane + 64*i];
      s += v.x + v.y + v.z + v.w;
      q += v.x*v.x + v.y*v.y + v.z*v.z + v.w*v.w;
    }
    #pragma unroll
    for (int off = 32; off; off >>= 1) { s += __shfl_xor(s, off); q += __shfl_xor(q, off); }
    if (lane == 0) {
      float mu = s * (1.f/CH);
      float var = q * (1.f/CH) - mu*mu;
      mu_s[row] = mu; rs_s[row] = rsqrtf(var + 1e-5f);
    }
  }
  __syncthreads();

  f32x4 acc[6];
  #pragma unroll
  for (int i = 0; i < 6; ++i) acc[i] = (f32x4){0.f, 0.f, 0.f, 0.f};

  for (int kc = 0; kc < CH; kc += K2_KC) {
    __syncthreads();
    // stage A: 64 rows x 64 k, LN applied, fp32 -> bf16
    #pragma unroll
    for (int i = 0; i < 4; ++i) {
      int j = tid + 256*i;
      int row = j >> 4, kq = j & 15;
      float4 v  = *(const float4*)(feat + (size_t)(r0 + row)*CH + kc + kq*4);
      float4 wv = *(const float4*)(lnw + kc + kq*4);
      float4 bv = *(const float4*)(lnb + kc + kq*4);
      float mu = mu_s[row], rs = rs_s[row];
      ushort4 pk = make_ushort4(f2bf((v.x - mu)*rs*wv.x + bv.x),
                                f2bf((v.y - mu)*rs*wv.y + bv.y),
                                f2bf((v.z - mu)*rs*wv.z + bv.z),
                                f2bf((v.w - mu)*rs*wv.w + bv.w));
      *(ushort4*)&A_lds[row][kq*4] = pk;
    }
    // stage W (B^T layout, pre-converted bf16): 96 rows x 64 k
    #pragma unroll
    for (int i = 0; i < 6; ++i) {
      int j = tid + 256*i;
      int row = j >> 4, kq = j & 15;
      ushort4 pk = *(const ushort4*)(Wb + (size_t)row*CH + kc + kq*4);
      *(ushort4*)&W_lds[row][kq*4] = pk;
    }
    __syncthreads();
    #pragma unroll
    for (int kt = 0; kt < 2; ++kt) {
      int krd = kt*32 + (lane >> 4)*8;
      bf16x8 af = *(const bf16x8*)&A_lds[w*16 + (lane & 15)][krd];
      #pragma unroll
      for (int ct = 0; ct < 6; ++ct) {
        bf16x8 bfr = *(const bf16x8*)&W_lds[ct*16 + (lane & 15)][krd];
        acc[ct] = mfma16(af, bfr, acc[ct]);
      }
    }
  }
  // epilogue: C/D layout col=lane&15, row=(lane>>4)*4+reg
  int rloc = w*16 + (lane >> 4)*4;
  int cl = lane & 15;
  #pragma unroll
  for (int ct = 0; ct < 6; ++ct)
    #pragma unroll
    for (int i = 0; i < 4; ++i)
      xin[(size_t)(r0 + rloc + i)*DIN + ct*16 + cl] = acc[ct][i];
}

// ---------------- K3: depthwise conv3 + silu + x_proj/dt_proj ----------------
// ugT/dgT are written TRANSPOSED: [b][d][t] so the scan reads t-contiguous.
#define K3_R 8
__launch_bounds__(128)
__global__ void k_conv_proj(const float* __restrict__ xin,
                            const float* __restrict__ cw, const float* __restrict__ cb,
                            const float* __restrict__ xBC, const float* __restrict__ M1t,
                            const float* __restrict__ dtb,
                            float* __restrict__ ugT, float* __restrict__ dgT,
                            float* __restrict__ Bg, float* __restrict__ Cg) {
  __shared__ float su[K3_R][DIN];
  const int b  = blockIdx.y;
  const int l0 = blockIdx.x * K3_R;
  const int t  = threadIdx.x;

  if (t < DIN) {
    float x[K3_R + 2];
    #pragma unroll
    for (int i = 0; i < K3_R + 2; ++i) {
      int li = l0 - 1 + i;
      x[i] = (li >= 0 && li < LEN) ? xin[((size_t)b*LEN + li)*DIN + t] : 0.f;
    }
    float w0 = cw[t*3], w1 = cw[t*3+1], w2 = cw[t*3+2], bb = cb[t];
    float ua[K3_R];
    #pragma unroll
    for (int r = 0; r < K3_R; ++r) {
      float c = w0*x[r] + w1*x[r+1] + w2*x[r+2] + bb;
      float uu = c / (1.f + __expf(-c));        // silu
      su[r][t] = uu;
      ua[r] = uu;
    }
    float* up = ugT + ((size_t)(b*DIN + t))*LEN + l0;
    *(float4*)(up)     = make_float4(ua[0], ua[1], ua[2], ua[3]);
    *(float4*)(up + 4) = make_float4(ua[4], ua[5], ua[6], ua[7]);
  }
  __syncthreads();
  if (t < DIN) {
    float z[K3_R];
    #pragma unroll
    for (int r = 0; r < K3_R; ++r) z[r] = dtb[t];
    for (int c = 0; c < DIN; ++c) {
      float m = M1t[c*DIN + t];                 // coalesced
      #pragma unroll
      for (int r = 0; r < K3_R; ++r) z[r] += su[r][c] * m;
    }
    float da[K3_R];
    #pragma unroll
    for (int r = 0; r < K3_R; ++r) {
      float zz = z[r];
      float sp = (zz > 20.f) ? zz : log1pf(__expf(zz));
      da[r] = 0.001f * sp;
    }
    float* dp = dgT + ((size_t)(b*DIN + t))*LEN + l0;
    *(float4*)(dp)     = make_float4(da[0], da[1], da[2], da[3]);
    *(float4*)(dp + 4) = make_float4(da[4], da[5], da[6], da[7]);
  } else if (t < DIN + 32) {
    int n = t - DIN;
    float s[K3_R];
    #pragma unroll
    for (int r = 0; r < K3_R; ++r) s[r] = 0.f;
    for (int c = 0; c < DIN; ++c) {
      float wv = xBC[c*32 + n];                 // coalesced
      #pragma unroll
      for (int r = 0; r < K3_R; ++r) s[r] += su[r][c] * wv;
    }
    #pragma unroll
    for (int r = 0; r < K3_R; ++r) {
      size_t row = (size_t)b*LEN + l0 + r;
      if (n < 16) Bg[row*NST + n]        = s[r];
      else        Cg[row*NST + (n - 16)] = s[r];
    }
  }
}

// ---------------- K4a: chunked scan pass 1 — per-chunk local state + sum(delta) ----------------
// group = 16 lanes (one per n) per (pair, chunk); 16 groups/block; grid (96, 8)
__launch_bounds__(256)
__global__ void k_scan1(const float* __restrict__ dgT, const float* __restrict__ ugT,
                        const float* __restrict__ Bg, const float* __restrict__ Alog,
                        float* __restrict__ carryS, float* __restrict__ carryD) {
  const int tid  = threadIdx.x;
  const int n    = tid & 15;
  const int pair = blockIdx.x * 16 + (tid >> 4);   // consecutive groups = consecutive d
  const int chunk = blockIdx.y;
  const int b = pair / DIN, d = pair - b*DIN;
  const float An = -__expf(Alog[d*NST + n]);
  const float* dp  = dgT + ((size_t)(b*DIN + d))*LEN + chunk*TCH;
  const float* up  = ugT + ((size_t)(b*DIN + d))*LEN + chunk*TCH;
  const float* bp_ = Bg + ((size_t)b*LEN + chunk*TCH)*NST + n;

  float s = 0.f, sdl = 0.f;
  #pragma unroll 2
  for (int tq = 0; tq < TCH/4; ++tq) {
    f32x4 dl4 = *(const f32x4*)(dp + tq*4);
    f32x4 uu4 = *(const f32x4*)(up + tq*4);
    #pragma unroll
    for (int j = 0; j < 4; ++j) {
      float dl = dl4[j];
      float bp = bp_[(size_t)(tq*4 + j)*NST];
      s = fmaf(__expf(dl*An), s, dl*bp*uu4[j]);
      sdl += dl;
    }
  }
  carryS[(size_t)(pair*NCHK + chunk)*16 + n] = s;
  if (n == 0) carryD[pair*NCHK + chunk] = sdl;
}

// ---------------- K4b: sequential carry combine across chunks ----------------
__launch_bounds__(256)
__global__ void k_scan2(const float* __restrict__ carryS, const float* __restrict__ carryD,
                        const float* __restrict__ Alog, float* __restrict__ xstart) {
  const int i = blockIdx.x * 256 + threadIdx.x;   // 0..24575: (pair, n)
  const int pair = i >> 4, n = i & 15;
  const int d = pair % DIN;
  const float An = -__expf(Alog[d*NST + n]);
  float x = 0.f;
  #pragma unroll
  for (int c = 0; c < NCHK; ++c) {
    xstart[(size_t)(pair*NCHK + c)*16 + n] = x;
    x = fmaf(__expf(An * carryD[pair*NCHK + c]), x, carryS[(size_t)(pair*NCHK + c)*16 + n]);
  }
}

// ---------------- K4c: chunked scan pass 2 — seeded recompute + y output ----------------
__launch_bounds__(256)
__global__ void k_scan3(const float* __restrict__ dgT, const float* __restrict__ ugT,
                        const float* __restrict__ Bg, const float* __restrict__ Cg,
                        const float* __restrict__ Alog, const float* __restrict__ Dp,
                        const float* __restrict__ xstart, unsigned short* __restrict__ yb) {
  const int tid  = threadIdx.x;
  const int n    = tid & 15;
  const int pair = blockIdx.x * 16 + (tid >> 4);
  const int chunk = blockIdx.y;
  const int b = pair / DIN, d = pair - b*DIN;
  const float An = -__expf(Alog[d*NST + n]);
  const float Dd = Dp[d];
  const float* dp  = dgT + ((size_t)(b*DIN + d))*LEN + chunk*TCH;
  const float* up  = ugT + ((size_t)(b*DIN + d))*LEN + chunk*TCH;
  const float* bp_ = Bg + ((size_t)b*LEN + chunk*TCH)*NST + n;
  const float* cp_ = Cg + ((size_t)b*LEN + chunk*TCH)*NST + n;
  unsigned short* yp = yb + ((size_t)b*LEN + chunk*TCH)*DIN + d;

  float s = xstart[(size_t)(pair*NCHK + chunk)*16 + n];
  #pragma unroll 2
  for (int tq = 0; tq < TCH/4; ++tq) {
    f32x4 dl4 = *(const f32x4*)(dp + tq*4);
    f32x4 uu4 = *(const f32x4*)(up + tq*4);
    #pragma unroll
    for (int j = 0; j < 4; ++j) {
      float dl = dl4[j];
      float bp = bp_[(size_t)(tq*4 + j)*NST];
      float cp = cp_[(size_t)(tq*4 + j)*NST];
      s = fmaf(__expf(dl*An), s, dl*bp*uu4[j]);
      float py = s * cp;
      py += __shfl_xor(py, 8);
      py += __shfl_xor(py, 4);
      py += __shfl_xor(py, 2);
      py += __shfl_xor(py, 1);
      if (n == 0) yp[(size_t)(tq*4 + j)*DIN] = f2bf(py + uu4[j]*Dd);
    }
  }
}

// ---------------- K5: out_proj (bf16 MFMA) + residual ----------------
#define K6_MR 128
#define K6_NC 128
#define K6_LD 104   // 208B row stride, 16B aligned

__launch_bounds__(256)
__global__ void k_outproj(const unsigned short* __restrict__ yb,
                          const unsigned short* __restrict__ Wb,  // (2048 x 96) bf16
                          const float* __restrict__ resid,
                          float* __restrict__ out) {
  __shared__ unsigned short Y_lds[K6_MR][K6_LD];
  __shared__ unsigned short W_lds[K6_NC][K6_LD];
  const int tid  = threadIdx.x;
  const int lane = tid & 63;
  const int w    = tid >> 6;
  const int r0   = blockIdx.y * K6_MR;
  const int c0   = blockIdx.x * K6_NC;

  #pragma unroll
  for (int i = 0; i < 12; ++i) {
    int j = tid + 256*i;
    int row = j / 24, q = j - row*24;
    *(ushort4*)&Y_lds[row][q*4] = *(const ushort4*)(yb + (size_t)(r0 + row)*DIN + q*4);
  }
  #pragma unroll
  for (int i = 0; i < 12; ++i) {
    int j = tid + 256*i;
    int row = j / 24, q = j - row*24;
    *(ushort4*)&W_lds[row][q*4] = *(const ushort4*)(Wb + (size_t)(c0 + row)*DIN + q*4);
  }
  __syncthreads();

  f32x4 acc[2][8];
  #pragma unroll
  for (int i = 0; i < 2; ++i)
    #pragma unroll
    for (int j = 0; j < 8; ++j) acc[i][j] = (f32x4){0.f, 0.f, 0.f, 0.f};

  #pragma unroll
  for (int kt = 0; kt < 3; ++kt) {     // K = 96 = 3 x 32
    int krd = kt*32 + (lane >> 4)*8;
    bf16x8 a0 = *(const bf16x8*)&Y_lds[w*32 +      (lane & 15)][krd];
    bf16x8 a1 = *(const bf16x8*)&Y_lds[w*32 + 16 + (lane & 15)][krd];
    #pragma unroll
    for (int ct = 0; ct < 8; ++ct) {
      bf16x8 bfr = *(const bf16x8*)&W_lds[ct*16 + (lane & 15)][krd];
      acc[0][ct] = mfma16(a0, bfr, acc[0][ct]);
      acc[1][ct] = mfma16(a1, bfr, acc[1][ct]);
    }
  }

  const int cl = lane & 15;
  const int rl = (lane >> 4)*4;
  #pragma unroll
  for (int i = 0; i < 2; ++i)
    #pragma unroll
    for (int ct = 0; ct < 8; ++ct)
      #pragma unroll
      for (int r = 0; r < 4; ++r) {
        size_t row = (size_t)(r0 + w*32 + i*16 + rl + r);
        size_t col = (size_t)(c0 + ct*16 + cl);
        size_t idx = row*CH + col;
        out[idx] = acc[i][ct][r] + resid[idx];
      }
}

extern "C" void kernel_launch(void* const* d_in, const int* in_sizes, int n_in,
                              void* d_out, int out_size, void* d_ws, size_t ws_size,
                              hipStream_t stream) {
  const float* feat = (const float*)d_in[0];
  const float* lnw  = (const float*)d_in[1];
  const float* lnb  = (const float*)d_in[2];
  const float* inW  = (const float*)d_in[3];
  const float* cw   = (const float*)d_in[4];
  const float* cb   = (const float*)d_in[5];
  const float* xW   = (const float*)d_in[6];
  const float* dtW  = (const float*)d_in[7];
  const float* dtb  = (const float*)d_in[8];
  const float* Alog = (const float*)d_in[9];
  const float* Dp   = (const float*)d_in[10];
  const float* outW = (const float*)d_in[11];
  float* out = (float*)d_out;

  char* ws = (char*)d_ws;
  size_t off = 0;
  auto alloc = [&](size_t bytes) { void* p = ws + off; off += (bytes + 255) & ~255ull; return p; };
  unsigned short* inWb  = (unsigned short*)alloc((size_t)DIN*CH*2);
  unsigned short* outWb = (unsigned short*)alloc((size_t)CH*DIN*2);
  float* M1t = (float*)alloc((size_t)DIN*DIN*4);
  float* xBC = (float*)alloc((size_t)DIN*32*4);
  float* xin = (float*)alloc((size_t)NROW*DIN*4);
  float* ugT = (float*)alloc((size_t)NROW*DIN*4);
  float* dgT = (float*)alloc((size_t)NROW*DIN*4);
  float* Bg  = (float*)alloc((size_t)NROW*NST*4);
  float* Cg  = (float*)alloc((size_t)NROW*NST*4);
  unsigned short* yb = (unsigned short*)alloc((size_t)NROW*DIN*2);
  float* carryS = (float*)alloc((size_t)NPAIR*NCHK*NST*4);
  float* carryD = (float*)alloc((size_t)NPAIR*NCHK*4);
  float* xstart = (float*)alloc((size_t)NPAIR*NCHK*NST*4);
  // total ~51 MB of d_ws

  hipLaunchKernelGGL(k_prep, dim3((DIN*CH + 255)/256), dim3(256), 0, stream,
                     inW, outW, xW, dtW, inWb, outWb, M1t, xBC);
  hipLaunchKernelGGL(k_ln_inproj, dim3(NROW/K2_ROWS), dim3(256), 0, stream,
                     feat, lnw, lnb, inWb, xin);
  hipLaunchKernelGGL(k_conv_proj, dim3(LEN/K3_R, BSZ), dim3(128), 0, stream,
                     xin, cw, cb, xBC, M1t, dtb, ugT, dgT, Bg, Cg);
  hipLaunchKernelGGL(k_scan1, dim3(NPAIR/16, NCHK), dim3(256), 0, stream,
                     dgT, ugT, Bg, Alog, carryS, carryD);
  hipLaunchKernelGGL(k_scan2, dim3(NPAIR*NST/256), dim3(256), 0, stream,
                     carryS, carryD, Alog, xstart);
  hipLaunchKernelGGL(k_scan3, dim3(NPAIR/16, NCHK), dim3(256), 0, stream,
                     dgT, ugT, Bg, Cg, Alog, Dp, xstart, yb);
  hipLaunchKernelGGL(k_outproj, dim3(CH/K6_NC, NROW/K6_MR), dim3(256), 0, stream,
                     yb, outWb, feat, out);
}

// Round 3
// 446.680 us; speedup vs baseline: 2.6525x; 1.0730x over previous
//
#include <hip/hip_runtime.h>
#include <hip/hip_bf16.h>

#define BSZ 16
#define LEN 2048
#define CH  2048
#define DIN 96
#define NST 16
#define RNK 6
#define NROW (BSZ*LEN)   // 32768
#define TCH  256
#define NCHK (LEN/TCH)   // 8
#define NPAIR (BSZ*DIN)  // 1536

typedef __attribute__((ext_vector_type(4))) float f32x4;
typedef __attribute__((ext_vector_type(8))) short bf16x8;

static __device__ __forceinline__ unsigned short f2bf(float f) {
  union { float f; unsigned u; } v; v.f = f;
  unsigned r = v.u + 0x7fff + ((v.u >> 16) & 1);   // RNE
  return (unsigned short)(r >> 16);
}

static __device__ __forceinline__ f32x4 mfma16(bf16x8 a, bf16x8 b, f32x4 c) {
  return __builtin_amdgcn_mfma_f32_16x16x32_bf16(a, b, c, 0, 0, 0);
}

// ---------------- K0: prep — W*lnw -> bf16, outW -> bf16, fold dtW@xW[:6] ----------------
__global__ void k_prep(const float* __restrict__ inW, const float* __restrict__ outW,
                       const float* __restrict__ xW, const float* __restrict__ dtW,
                       const float* __restrict__ lnw,
                       unsigned short* __restrict__ inWb, unsigned short* __restrict__ outWb,
                       float* __restrict__ M1t, float* __restrict__ xBC) {
  int i = blockIdx.x * 256 + threadIdx.x;
  if (i < DIN*CH)  inWb[i]  = f2bf(inW[i] * lnw[i & (CH-1)]);   // fold lnw into W cols
  if (i < CH*DIN)  outWb[i] = f2bf(outW[i]);
  if (i < DIN*DIN) {                 // M1t[c*96+d] = sum_r dtW[d,r]*xW[r,c]
    int c = i / DIN, d = i - c*DIN;
    float s = 0.f;
    #pragma unroll
    for (int r = 0; r < RNK; ++r) s += dtW[d*RNK + r] * xW[r*DIN + c];
    M1t[i] = s;
  }
  if (i < DIN*32) {                  // xBC[c*32+n] = xW[6+n, c]  (transposed B/C proj)
    int c = i / 32, n = i - c*32;
    xBC[i] = xW[(RNK + n)*DIN + c];
  }
}

// ---------------- K0b: pvec[d] = sum_c lnw[c]*W[d,c], qvec[d] = sum_c lnb[c]*W[d,c] ----------------
__launch_bounds__(256)
__global__ void k_prep2(const float* __restrict__ inW, const float* __restrict__ lnw,
                        const float* __restrict__ lnb,
                        float* __restrict__ pvec, float* __restrict__ qvec) {
  __shared__ float sp_[4], sq_[4];
  const int d = blockIdx.x;
  const int tid = threadIdx.x;
  const float4* w4 = (const float4*)(inW + (size_t)d*CH);
  const float4* a4 = (const float4*)lnw;
  const float4* b4 = (const float4*)lnb;
  float sp = 0.f, sq = 0.f;
  for (int j = tid; j < CH/4; j += 256) {
    float4 w = w4[j], a = a4[j], b = b4[j];
    sp += w.x*a.x + w.y*a.y + w.z*a.z + w.w*a.w;
    sq += w.x*b.x + w.y*b.y + w.z*b.z + w.w*b.w;
  }
  #pragma unroll
  for (int off = 32; off; off >>= 1) { sp += __shfl_xor(sp, off); sq += __shfl_xor(sq, off); }
  if ((tid & 63) == 0) { sp_[tid>>6] = sp; sq_[tid>>6] = sq; }
  __syncthreads();
  if (tid == 0) {
    pvec[d] = sp_[0] + sp_[1] + sp_[2] + sp_[3];
    qvec[d] = sq_[0] + sq_[1] + sq_[2] + sq_[3];
  }
}

// ---------------- K2: fused LN + in_proj, single-pass (folded LN, reg-A, W-chunk LDS) ----------------
// xin[r,:] = rs*(feat[r,:] @ Wln^T) - rs*mu*p + q ; stats accumulated inline.
#define K2_KC 256
#define K2_WLD 264   // 528B row stride = 33 x 16B (granule stride 1 mod 8 -> 2-way max)

__launch_bounds__(256)
__global__ void k_ln_inproj(const float* __restrict__ feat,
                            const unsigned short* __restrict__ Wb,
                            const float* __restrict__ pvec, const float* __restrict__ qvec,
                            float* __restrict__ xin) {
  __shared__ unsigned short W_lds[DIN][K2_WLD];

  const int tid  = threadIdx.x;
  const int lane = tid & 63;
  const int w    = tid >> 6;
  const int r    = lane & 15;     // row within wave's 16-row tile (B-operand index)
  const int g    = lane >> 4;     // k-quadrant
  const int r0   = blockIdx.x * 64;

  const float* arow = feat + (size_t)(r0 + w*16 + r) * CH;

  f32x4 acc[6];
  #pragma unroll
  for (int i = 0; i < 6; ++i) acc[i] = (f32x4){0.f, 0.f, 0.f, 0.f};
  float s = 0.f, q = 0.f;

  for (int kc = 0; kc < CH; kc += K2_KC) {
    __syncthreads();
    // stage W chunk: 96 rows x 256 k (bf16), 12 x 16B per thread
    #pragma unroll
    for (int i = 0; i < 12; ++i) {
      int j = tid + 256*i;
      int row = j >> 5, c16 = j & 31;
      *(uint4*)&W_lds[row][c16*8] = *(const uint4*)(Wb + (size_t)row*CH + kc + c16*8);
    }
    __syncthreads();
    #pragma unroll
    for (int t = 0; t < 8; ++t) {
      const float* ap = arow + kc + t*32 + g*8;
      float4 v0 = *(const float4*)ap;
      float4 v1 = *(const float4*)(ap + 4);
      s += v0.x + v0.y + v0.z + v0.w + v1.x + v1.y + v1.z + v1.w;
      q = fmaf(v0.x, v0.x, q); q = fmaf(v0.y, v0.y, q);
      q = fmaf(v0.z, v0.z, q); q = fmaf(v0.w, v0.w, q);
      q = fmaf(v1.x, v1.x, q); q = fmaf(v1.y, v1.y, q);
      q = fmaf(v1.z, v1.z, q); q = fmaf(v1.w, v1.w, q);
      union { bf16x8 v; unsigned short u[8]; } af;
      af.u[0] = f2bf(v0.x); af.u[1] = f2bf(v0.y); af.u[2] = f2bf(v0.z); af.u[3] = f2bf(v0.w);
      af.u[4] = f2bf(v1.x); af.u[5] = f2bf(v1.y); af.u[6] = f2bf(v1.z); af.u[7] = f2bf(v1.w);
      const int krd = t*32 + g*8;
      #pragma unroll
      for (int ct = 0; ct < 6; ++ct) {
        bf16x8 wf = *(const bf16x8*)&W_lds[ct*16 + r][krd];
        acc[ct] = mfma16(wf, af.v, acc[ct]);   // M-dim = W cols, N-dim = feat rows
      }
    }
  }

  // finish row stats: lanes {r, r+16, r+32, r+48} cover disjoint k-subsets of row r
  s += __shfl_xor(s, 16); s += __shfl_xor(s, 32);
  q += __shfl_xor(q, 16); q += __shfl_xor(q, 32);
  const float mu = s * (1.f/CH);
  const float rs = rsqrtf(q*(1.f/CH) - mu*mu + 1e-5f);

  // epilogue: lane holds row (w*16+r), cols ct*16 + g*4 + {0..3} -> float4 stores
  float* orow = xin + (size_t)(r0 + w*16 + r) * DIN;
  #pragma unroll
  for (int ct = 0; ct < 6; ++ct) {
    const int col = ct*16 + g*4;
    float4 pv = *(const float4*)(pvec + col);
    float4 qv = *(const float4*)(qvec + col);
    f32x4 a = acc[ct];
    float4 o;
    o.x = rs*a[0] - rs*mu*pv.x + qv.x;
    o.y = rs*a[1] - rs*mu*pv.y + qv.y;
    o.z = rs*a[2] - rs*mu*pv.z + qv.z;
    o.w = rs*a[3] - rs*mu*pv.w + qv.w;
    *(float4*)(orow + col) = o;
  }
}

// ---------------- K3: depthwise conv3 + silu + x_proj/dt_proj ----------------
// ugT/dgT are written TRANSPOSED: [b][d][t] so the scan reads t-contiguous.
#define K3_R 8
__launch_bounds__(128)
__global__ void k_conv_proj(const float* __restrict__ xin,
                            const float* __restrict__ cw, const float* __restrict__ cb,
                            const float* __restrict__ xBC, const float* __restrict__ M1t,
                            const float* __restrict__ dtb,
                            float* __restrict__ ugT, float* __restrict__ dgT,
                            float* __restrict__ Bg, float* __restrict__ Cg) {
  __shared__ float su[K3_R][DIN];
  const int b  = blockIdx.y;
  const int l0 = blockIdx.x * K3_R;
  const int t  = threadIdx.x;

  if (t < DIN) {
    float x[K3_R + 2];
    #pragma unroll
    for (int i = 0; i < K3_R + 2; ++i) {
      int li = l0 - 1 + i;
      x[i] = (li >= 0 && li < LEN) ? xin[((size_t)b*LEN + li)*DIN + t] : 0.f;
    }
    float w0 = cw[t*3], w1 = cw[t*3+1], w2 = cw[t*3+2], bb = cb[t];
    float ua[K3_R];
    #pragma unroll
    for (int r = 0; r < K3_R; ++r) {
      float c = w0*x[r] + w1*x[r+1] + w2*x[r+2] + bb;
      float uu = c / (1.f + __expf(-c));        // silu
      su[r][t] = uu;
      ua[r] = uu;
    }
    float* up = ugT + ((size_t)(b*DIN + t))*LEN + l0;
    *(float4*)(up)     = make_float4(ua[0], ua[1], ua[2], ua[3]);
    *(float4*)(up + 4) = make_float4(ua[4], ua[5], ua[6], ua[7]);
  }
  __syncthreads();
  if (t < DIN) {
    float z[K3_R];
    #pragma unroll
    for (int r = 0; r < K3_R; ++r) z[r] = dtb[t];
    for (int c = 0; c < DIN; ++c) {
      float m = M1t[c*DIN + t];                 // coalesced
      #pragma unroll
      for (int r = 0; r < K3_R; ++r) z[r] += su[r][c] * m;
    }
    float da[K3_R];
    #pragma unroll
    for (int r = 0; r < K3_R; ++r) {
      float zz = z[r];
      float sp = (zz > 20.f) ? zz : log1pf(__expf(zz));
      da[r] = 0.001f * sp;
    }
    float* dp = dgT + ((size_t)(b*DIN + t))*LEN + l0;
    *(float4*)(dp)     = make_float4(da[0], da[1], da[2], da[3]);
    *(float4*)(dp + 4) = make_float4(da[4], da[5], da[6], da[7]);
  } else if (t < DIN + 32) {
    int n = t - DIN;
    float s[K3_R];
    #pragma unroll
    for (int r = 0; r < K3_R; ++r) s[r] = 0.f;
    for (int c = 0; c < DIN; ++c) {
      float wv = xBC[c*32 + n];                 // coalesced
      #pragma unroll
      for (int r = 0; r < K3_R; ++r) s[r] += su[r][c] * wv;
    }
    #pragma unroll
    for (int r = 0; r < K3_R; ++r) {
      size_t row = (size_t)b*LEN + l0 + r;
      if (n < 16) Bg[row*NST + n]        = s[r];
      else        Cg[row*NST + (n - 16)] = s[r];
    }
  }
}

// ---------------- K4a: chunked scan pass 1 — per-chunk local state + sum(delta) ----------------
__launch_bounds__(256)
__global__ void k_scan1(const float* __restrict__ dgT, const float* __restrict__ ugT,
                        const float* __restrict__ Bg, const float* __restrict__ Alog,
                        float* __restrict__ carryS, float* __restrict__ carryD) {
  const int tid  = threadIdx.x;
  const int n    = tid & 15;
  const int pair = blockIdx.x * 16 + (tid >> 4);
  const int chunk = blockIdx.y;
  const int b = pair / DIN, d = pair - b*DIN;
  const float An = -__expf(Alog[d*NST + n]);
  const float* dp  = dgT + ((size_t)(b*DIN + d))*LEN + chunk*TCH;
  const float* up  = ugT + ((size_t)(b*DIN + d))*LEN + chunk*TCH;
  const float* bp_ = Bg + ((size_t)b*LEN + chunk*TCH)*NST + n;

  float s = 0.f, sdl = 0.f;
  #pragma unroll 2
  for (int tq = 0; tq < TCH/4; ++tq) {
    f32x4 dl4 = *(const f32x4*)(dp + tq*4);
    f32x4 uu4 = *(const f32x4*)(up + tq*4);
    #pragma unroll
    for (int j = 0; j < 4; ++j) {
      float dl = dl4[j];
      float bp = bp_[(size_t)(tq*4 + j)*NST];
      s = fmaf(__expf(dl*An), s, dl*bp*uu4[j]);
      sdl += dl;
    }
  }
  carryS[(size_t)(pair*NCHK + chunk)*16 + n] = s;
  if (n == 0) carryD[pair*NCHK + chunk] = sdl;
}

// ---------------- K4b: sequential carry combine across chunks ----------------
__launch_bounds__(256)
__global__ void k_scan2(const float* __restrict__ carryS, const float* __restrict__ carryD,
                        const float* __restrict__ Alog, float* __restrict__ xstart) {
  const int i = blockIdx.x * 256 + threadIdx.x;   // 0..24575: (pair, n)
  const int pair = i >> 4, n = i & 15;
  const int d = pair % DIN;
  const float An = -__expf(Alog[d*NST + n]);
  float x = 0.f;
  #pragma unroll
  for (int c = 0; c < NCHK; ++c) {
    xstart[(size_t)(pair*NCHK + c)*16 + n] = x;
    x = fmaf(__expf(An * carryD[pair*NCHK + c]), x, carryS[(size_t)(pair*NCHK + c)*16 + n]);
  }
}

// ---------------- K4c: chunked scan pass 2 — seeded recompute + y output ----------------
__launch_bounds__(256)
__global__ void k_scan3(const float* __restrict__ dgT, const float* __restrict__ ugT,
                        const float* __restrict__ Bg, const float* __restrict__ Cg,
                        const float* __restrict__ Alog, const float* __restrict__ Dp,
                        const float* __restrict__ xstart, unsigned short* __restrict__ yb) {
  const int tid  = threadIdx.x;
  const int n    = tid & 15;
  const int pair = blockIdx.x * 16 + (tid >> 4);
  const int chunk = blockIdx.y;
  const int b = pair / DIN, d = pair - b*DIN;
  const float An = -__expf(Alog[d*NST + n]);
  const float Dd = Dp[d];
  const float* dp  = dgT + ((size_t)(b*DIN + d))*LEN + chunk*TCH;
  const float* up  = ugT + ((size_t)(b*DIN + d))*LEN + chunk*TCH;
  const float* bp_ = Bg + ((size_t)b*LEN + chunk*TCH)*NST + n;
  const float* cp_ = Cg + ((size_t)b*LEN + chunk*TCH)*NST + n;
  unsigned short* yp = yb + ((size_t)b*LEN + chunk*TCH)*DIN + d;

  float s = xstart[(size_t)(pair*NCHK + chunk)*16 + n];
  #pragma unroll 2
  for (int tq = 0; tq < TCH/4; ++tq) {
    f32x4 dl4 = *(const f32x4*)(dp + tq*4);
    f32x4 uu4 = *(const f32x4*)(up + tq*4);
    #pragma unroll
    for (int j = 0; j < 4; ++j) {
      float dl = dl4[j];
      float bp = bp_[(size_t)(tq*4 + j)*NST];
      float cp = cp_[(size_t)(tq*4 + j)*NST];
      s = fmaf(__expf(dl*An), s, dl*bp*uu4[j]);
      float py = s * cp;
      py += __shfl_xor(py, 8);
      py += __shfl_xor(py, 4);
      py += __shfl_xor(py, 2);
      py += __shfl_xor(py, 1);
      if (n == 0) yp[(size_t)(tq*4 + j)*DIN] = f2bf(py + uu4[j]*Dd);
    }
  }
}

// ---------------- K5: out_proj (bf16 MFMA, swapped operands) + residual, float4 epilogue ----------------
#define K6_MR 128
#define K6_NC 128
#define K6_LD 104   // 208B row stride, 16B aligned

__launch_bounds__(256)
__global__ void k_outproj(const unsigned short* __restrict__ yb,
                          const unsigned short* __restrict__ Wb,  // (2048 x 96) bf16
                          const float* __restrict__ resid,
                          float* __restrict__ out) {
  __shared__ unsigned short Y_lds[K6_MR][K6_LD];
  __shared__ unsigned short W_lds[K6_NC][K6_LD];
  const int tid  = threadIdx.x;
  const int lane = tid & 63;
  const int w    = tid >> 6;
  const int r    = lane & 15;
  const int g    = lane >> 4;
  const int r0   = blockIdx.y * K6_MR;
  const int c0   = blockIdx.x * K6_NC;

  #pragma unroll
  for (int i = 0; i < 12; ++i) {
    int j = tid + 256*i;
    int row = j / 24, q = j - row*24;
    *(ushort4*)&Y_lds[row][q*4] = *(const ushort4*)(yb + (size_t)(r0 + row)*DIN + q*4);
  }
  #pragma unroll
  for (int i = 0; i < 12; ++i) {
    int j = tid + 256*i;
    int row = j / 24, q = j - row*24;
    *(ushort4*)&W_lds[row][q*4] = *(const ushort4*)(Wb + (size_t)(c0 + row)*DIN + q*4);
  }
  __syncthreads();

  f32x4 acc[8][2];
  #pragma unroll
  for (int i = 0; i < 8; ++i)
    #pragma unroll
    for (int j = 0; j < 2; ++j) acc[i][j] = (f32x4){0.f, 0.f, 0.f, 0.f};

  #pragma unroll
  for (int kt = 0; kt < 3; ++kt) {     // K = 96 = 3 x 32
    const int krd = kt*32 + g*8;
    bf16x8 y0 = *(const bf16x8*)&Y_lds[w*32 +      r][krd];
    bf16x8 y1 = *(const bf16x8*)&Y_lds[w*32 + 16 + r][krd];
    #pragma unroll
    for (int ci = 0; ci < 8; ++ci) {
      bf16x8 wf = *(const bf16x8*)&W_lds[ci*16 + r][krd];
      acc[ci][0] = mfma16(wf, y0, acc[ci][0]);   // M-dim = out cols, N-dim = out rows
      acc[ci][1] = mfma16(wf, y1, acc[ci][1]);
    }
  }

  // epilogue: lane -> row (w*32 + ri*16 + r), cols ci*16 + g*4 + {0..3}: float4 RMW
  #pragma unroll
  for (int ci = 0; ci < 8; ++ci)
    #pragma unroll
    for (int ri = 0; ri < 2; ++ri) {
      size_t row = (size_t)(r0 + w*32 + ri*16 + r);
      size_t col = (size_t)(c0 + ci*16 + g*4);
      const float4 rv = *(const float4*)(resid + row*CH + col);
      f32x4 a = acc[ci][ri];
      float4 o = make_float4(a[0] + rv.x, a[1] + rv.y, a[2] + rv.z, a[3] + rv.w);
      *(float4*)(out + row*CH + col) = o;
    }
}

extern "C" void kernel_launch(void* const* d_in, const int* in_sizes, int n_in,
                              void* d_out, int out_size, void* d_ws, size_t ws_size,
                              hipStream_t stream) {
  const float* feat = (const float*)d_in[0];
  const float* lnw  = (const float*)d_in[1];
  const float* lnb  = (const float*)d_in[2];
  const float* inW  = (const float*)d_in[3];
  const float* cw   = (const float*)d_in[4];
  const float* cb   = (const float*)d_in[5];
  const float* xW   = (const float*)d_in[6];
  const float* dtW  = (const float*)d_in[7];
  const float* dtb  = (const float*)d_in[8];
  const float* Alog = (const float*)d_in[9];
  const float* Dp   = (const float*)d_in[10];
  const float* outW = (const float*)d_in[11];
  float* out = (float*)d_out;

  char* ws = (char*)d_ws;
  size_t off = 0;
  auto alloc = [&](size_t bytes) { void* p = ws + off; off += (bytes + 255) & ~255ull; return p; };
  unsigned short* inWb  = (unsigned short*)alloc((size_t)DIN*CH*2);
  unsigned short* outWb = (unsigned short*)alloc((size_t)CH*DIN*2);
  float* M1t = (float*)alloc((size_t)DIN*DIN*4);
  float* xBC = (float*)alloc((size_t)DIN*32*4);
  float* pvec = (float*)alloc((size_t)DIN*4);
  float* qvec = (float*)alloc((size_t)DIN*4);
  float* xin = (float*)alloc((size_t)NROW*DIN*4);
  float* ugT = (float*)alloc((size_t)NROW*DIN*4);
  float* dgT = (float*)alloc((size_t)NROW*DIN*4);
  float* Bg  = (float*)alloc((size_t)NROW*NST*4);
  float* Cg  = (float*)alloc((size_t)NROW*NST*4);
  unsigned short* yb = (unsigned short*)alloc((size_t)NROW*DIN*2);
  float* carryS = (float*)alloc((size_t)NPAIR*NCHK*NST*4);
  float* carryD = (float*)alloc((size_t)NPAIR*NCHK*4);
  float* xstart = (float*)alloc((size_t)NPAIR*NCHK*NST*4);

  hipLaunchKernelGGL(k_prep, dim3((DIN*CH + 255)/256), dim3(256), 0, stream,
                     inW, outW, xW, dtW, lnw, inWb, outWb, M1t, xBC);
  hipLaunchKernelGGL(k_prep2, dim3(DIN), dim3(256), 0, stream,
                     inW, lnw, lnb, pvec, qvec);
  hipLaunchKernelGGL(k_ln_inproj, dim3(NROW/64), dim3(256), 0, stream,
                     feat, inWb, pvec, qvec, xin);
  hipLaunchKernelGGL(k_conv_proj, dim3(LEN/K3_R, BSZ), dim3(128), 0, stream,
                     xin, cw, cb, xBC, M1t, dtb, ugT, dgT, Bg, Cg);
  hipLaunchKernelGGL(k_scan1, dim3(NPAIR/16, NCHK), dim3(256), 0, stream,
                     dgT, ugT, Bg, Alog, carryS, carryD);
  hipLaunchKernelGGL(k_scan2, dim3(NPAIR*NST/256), dim3(256), 0, stream,
                     carryS, carryD, Alog, xstart);
  hipLaunchKernelGGL(k_scan3, dim3(NPAIR/16, NCHK), dim3(256), 0, stream,
                     dgT, ugT, Bg, Cg, Alog, Dp, xstart, yb);
  hipLaunchKernelGGL(k_outproj, dim3(CH/K6_NC, NROW/K6_MR), dim3(256), 0, stream,
                     yb, outWb, feat, out);
}

// Round 5
// 437.460 us; speedup vs baseline: 2.7084x; 1.0211x over previous
//
#include <hip/hip_runtime.h>
#include <hip/hip_bf16.h>

#define BSZ 16
#define LEN 2048
#define CH  2048
#define DIN 96
#define NST 16
#define RNK 6
#define NROW (BSZ*LEN)   // 32768
#define TCH  256
#define NCHK (LEN/TCH)   // 8
#define NPAIR (BSZ*DIN)  // 1536

typedef __attribute__((ext_vector_type(4))) float f32x4;
typedef __attribute__((ext_vector_type(8))) short bf16x8;

static __device__ __forceinline__ unsigned short f2bf(float f) {
  union { float f; unsigned u; } v; v.f = f;
  unsigned r = v.u + 0x7fff + ((v.u >> 16) & 1);   // RNE
  return (unsigned short)(r >> 16);
}

static __device__ __forceinline__ f32x4 mfma16(bf16x8 a, bf16x8 b, f32x4 c) {
  return __builtin_amdgcn_mfma_f32_16x16x32_bf16(a, b, c, 0, 0, 0);
}

// ---------------- K0: prep — W*lnw -> bf16, outW -> bf16, fold dtW@xW[:6] ----------------
__global__ void k_prep(const float* __restrict__ inW, const float* __restrict__ outW,
                       const float* __restrict__ xW, const float* __restrict__ dtW,
                       const float* __restrict__ lnw,
                       unsigned short* __restrict__ inWb, unsigned short* __restrict__ outWb,
                       float* __restrict__ M1t, float* __restrict__ xBC) {
  int i = blockIdx.x * 256 + threadIdx.x;
  if (i < DIN*CH)  inWb[i]  = f2bf(inW[i] * lnw[i & (CH-1)]);   // fold lnw into W cols
  if (i < CH*DIN)  outWb[i] = f2bf(outW[i]);
  if (i < DIN*DIN) {                 // M1t[c*96+d] = sum_r dtW[d,r]*xW[r,c]
    int c = i / DIN, d = i - c*DIN;
    float s = 0.f;
    #pragma unroll
    for (int r = 0; r < RNK; ++r) s += dtW[d*RNK + r] * xW[r*DIN + c];
    M1t[i] = s;
  }
  if (i < DIN*32) {                  // xBC[c*32+n] = xW[6+n, c]  (transposed B/C proj)
    int c = i / 32, n = i - c*32;
    xBC[i] = xW[(RNK + n)*DIN + c];
  }
}

// ---------------- K0b: pvec[d] = sum_c lnw[c]*W[d,c], qvec[d] = sum_c lnb[c]*W[d,c] ----------------
__launch_bounds__(256)
__global__ void k_prep2(const float* __restrict__ inW, const float* __restrict__ lnw,
                        const float* __restrict__ lnb,
                        float* __restrict__ pvec, float* __restrict__ qvec) {
  __shared__ float sp_[4], sq_[4];
  const int d = blockIdx.x;
  const int tid = threadIdx.x;
  const float4* w4 = (const float4*)(inW + (size_t)d*CH);
  const float4* a4 = (const float4*)lnw;
  const float4* b4 = (const float4*)lnb;
  float sp = 0.f, sq = 0.f;
  for (int j = tid; j < CH/4; j += 256) {
    float4 w = w4[j], a = a4[j], b = b4[j];
    sp += w.x*a.x + w.y*a.y + w.z*a.z + w.w*a.w;
    sq += w.x*b.x + w.y*b.y + w.z*b.z + w.w*b.w;
  }
  #pragma unroll
  for (int off = 32; off; off >>= 1) { sp += __shfl_xor(sp, off); sq += __shfl_xor(sq, off); }
  if ((tid & 63) == 0) { sp_[tid>>6] = sp; sq_[tid>>6] = sq; }
  __syncthreads();
  if (tid == 0) {
    pvec[d] = sp_[0] + sp_[1] + sp_[2] + sp_[3];
    qvec[d] = sq_[0] + sq_[1] + sq_[2] + sq_[3];
  }
}

// ---------------- K2: fused LN + in_proj, single-pass (folded LN, reg-A, W-chunk LDS) ----------------
// xin[r,:] = rs*(feat[r,:] @ Wln^T) - rs*mu*p + q ; stats accumulated inline.
#define K2_KC 128
#define K2_WLD 136   // 272B row stride = 17 x 16B granules (1 mod 8 -> 2-way max = free)

__launch_bounds__(256)
__global__ void k_ln_inproj(const float* __restrict__ feat,
                            const unsigned short* __restrict__ Wb,
                            const float* __restrict__ pvec, const float* __restrict__ qvec,
                            float* __restrict__ xin) {
  __shared__ unsigned short W_lds[DIN][K2_WLD];

  const int tid  = threadIdx.x;
  const int lane = tid & 63;
  const int w    = tid >> 6;
  const int r    = lane & 15;     // row within wave's 16-row tile (B-operand index)
  const int g    = lane >> 4;     // k-quadrant
  const int r0   = blockIdx.x * 64;

  const float* arow = feat + (size_t)(r0 + w*16 + r) * CH;

  f32x4 acc[6];
  #pragma unroll
  for (int i = 0; i < 6; ++i) acc[i] = (f32x4){0.f, 0.f, 0.f, 0.f};
  float s = 0.f, q = 0.f;

  for (int kc = 0; kc < CH; kc += K2_KC) {
    __syncthreads();
    // stage W chunk: 96 rows x 128 k (bf16) = 16 granules/row = 1536 items = 6 x 256
    #pragma unroll
    for (int i = 0; i < 6; ++i) {
      int j = tid + 256*i;
      int row = j >> 4, c16 = j & 15;
      *(uint4*)&W_lds[row][c16*8] = *(const uint4*)(Wb + (size_t)row*CH + kc + c16*8);
    }
    __syncthreads();
    #pragma unroll
    for (int t = 0; t < 4; ++t) {
      const float* ap = arow + kc + t*32 + g*8;
      float4 v0 = *(const float4*)ap;
      float4 v1 = *(const float4*)(ap + 4);
      s += v0.x + v0.y + v0.z + v0.w + v1.x + v1.y + v1.z + v1.w;
      q = fmaf(v0.x, v0.x, q); q = fmaf(v0.y, v0.y, q);
      q = fmaf(v0.z, v0.z, q); q = fmaf(v0.w, v0.w, q);
      q = fmaf(v1.x, v1.x, q); q = fmaf(v1.y, v1.y, q);
      q = fmaf(v1.z, v1.z, q); q = fmaf(v1.w, v1.w, q);
      union { bf16x8 v; unsigned short u[8]; } af;
      af.u[0] = f2bf(v0.x); af.u[1] = f2bf(v0.y); af.u[2] = f2bf(v0.z); af.u[3] = f2bf(v0.w);
      af.u[4] = f2bf(v1.x); af.u[5] = f2bf(v1.y); af.u[6] = f2bf(v1.z); af.u[7] = f2bf(v1.w);
      const int krd = t*32 + g*8;
      #pragma unroll
      for (int ct = 0; ct < 6; ++ct) {
        bf16x8 wf = *(const bf16x8*)&W_lds[ct*16 + r][krd];
        acc[ct] = mfma16(wf, af.v, acc[ct]);   // M-dim = W cols, N-dim = feat rows
      }
    }
  }

  // finish row stats: lanes {r, r+16, r+32, r+48} cover disjoint k-subsets of row r
  s += __shfl_xor(s, 16); s += __shfl_xor(s, 32);
  q += __shfl_xor(q, 16); q += __shfl_xor(q, 32);
  const float mu = s * (1.f/CH);
  const float rs = rsqrtf(q*(1.f/CH) - mu*mu + 1e-5f);

  // epilogue: lane holds row (w*16+r), cols ct*16 + g*4 + {0..3} -> float4 stores
  float* orow = xin + (size_t)(r0 + w*16 + r) * DIN;
  #pragma unroll
  for (int ct = 0; ct < 6; ++ct) {
    const int col = ct*16 + g*4;
    float4 pv = *(const float4*)(pvec + col);
    float4 qv = *(const float4*)(qvec + col);
    f32x4 a = acc[ct];
    float4 o;
    o.x = rs*a[0] - rs*mu*pv.x + qv.x;
    o.y = rs*a[1] - rs*mu*pv.y + qv.y;
    o.z = rs*a[2] - rs*mu*pv.z + qv.z;
    o.w = rs*a[3] - rs*mu*pv.w + qv.w;
    *(float4*)(orow + col) = o;
  }
}

// ---------------- K3: depthwise conv3 + silu + x_proj/dt_proj ----------------
// ugT/dgT are written TRANSPOSED: [b][d][t] so the scan reads t-contiguous.
#define K3_R 8
__launch_bounds__(128)
__global__ void k_conv_proj(const float* __restrict__ xin,
                            const float* __restrict__ cw, const float* __restrict__ cb,
                            const float* __restrict__ xBC, const float* __restrict__ M1t,
                            const float* __restrict__ dtb,
                            float* __restrict__ ugT, float* __restrict__ dgT,
                            float* __restrict__ Bg, float* __restrict__ Cg) {
  __shared__ float su[K3_R][DIN];
  const int b  = blockIdx.y;
  const int l0 = blockIdx.x * K3_R;
  const int t  = threadIdx.x;

  if (t < DIN) {
    float x[K3_R + 2];
    #pragma unroll
    for (int i = 0; i < K3_R + 2; ++i) {
      int li = l0 - 1 + i;
      x[i] = (li >= 0 && li < LEN) ? xin[((size_t)b*LEN + li)*DIN + t] : 0.f;
    }
    float w0 = cw[t*3], w1 = cw[t*3+1], w2 = cw[t*3+2], bb = cb[t];
    float ua[K3_R];
    #pragma unroll
    for (int r = 0; r < K3_R; ++r) {
      float c = w0*x[r] + w1*x[r+1] + w2*x[r+2] + bb;
      float uu = c / (1.f + __expf(-c));        // silu
      su[r][t] = uu;
      ua[r] = uu;
    }
    float* up = ugT + ((size_t)(b*DIN + t))*LEN + l0;
    *(float4*)(up)     = make_float4(ua[0], ua[1], ua[2], ua[3]);
    *(float4*)(up + 4) = make_float4(ua[4], ua[5], ua[6], ua[7]);
  }
  __syncthreads();
  if (t < DIN) {
    float z[K3_R];
    #pragma unroll
    for (int r = 0; r < K3_R; ++r) z[r] = dtb[t];
    for (int c = 0; c < DIN; ++c) {
      float m = M1t[c*DIN + t];                 // coalesced
      #pragma unroll
      for (int r = 0; r < K3_R; ++r) z[r] += su[r][c] * m;
    }
    float da[K3_R];
    #pragma unroll
    for (int r = 0; r < K3_R; ++r) {
      float zz = z[r];
      float sp = (zz > 20.f) ? zz : log1pf(__expf(zz));
      da[r] = 0.001f * sp;
    }
    float* dp = dgT + ((size_t)(b*DIN + t))*LEN + l0;
    *(float4*)(dp)     = make_float4(da[0], da[1], da[2], da[3]);
    *(float4*)(dp + 4) = make_float4(da[4], da[5], da[6], da[7]);
  } else if (t < DIN + 32) {
    int n = t - DIN;
    float s[K3_R];
    #pragma unroll
    for (int r = 0; r < K3_R; ++r) s[r] = 0.f;
    for (int c = 0; c < DIN; ++c) {
      float wv = xBC[c*32 + n];                 // coalesced
      #pragma unroll
      for (int r = 0; r < K3_R; ++r) s[r] += su[r][c] * wv;
    }
    #pragma unroll
    for (int r = 0; r < K3_R; ++r) {
      size_t row = (size_t)b*LEN + l0 + r;
      if (n < 16) Bg[row*NST + n]        = s[r];
      else        Cg[row*NST + (n - 16)] = s[r];
    }
  }
}

// ---------------- K4a: chunked scan pass 1 — per-chunk local state + sum(delta) ----------------
__launch_bounds__(256)
__global__ void k_scan1(const float* __restrict__ dgT, const float* __restrict__ ugT,
                        const float* __restrict__ Bg, const float* __restrict__ Alog,
                        float* __restrict__ carryS, float* __restrict__ carryD) {
  const int tid  = threadIdx.x;
  const int n    = tid & 15;
  const int pair = blockIdx.x * 16 + (tid >> 4);
  const int chunk = blockIdx.y;
  const int b = pair / DIN, d = pair - b*DIN;
  const float An = -__expf(Alog[d*NST + n]);
  const float* dp  = dgT + ((size_t)(b*DIN + d))*LEN + chunk*TCH;
  const float* up  = ugT + ((size_t)(b*DIN + d))*LEN + chunk*TCH;
  const float* bp_ = Bg + ((size_t)b*LEN + chunk*TCH)*NST + n;

  float s = 0.f, sdl = 0.f;
  #pragma unroll 2
  for (int tq = 0; tq < TCH/4; ++tq) {
    f32x4 dl4 = *(const f32x4*)(dp + tq*4);
    f32x4 uu4 = *(const f32x4*)(up + tq*4);
    #pragma unroll
    for (int j = 0; j < 4; ++j) {
      float dl = dl4[j];
      float bp = bp_[(size_t)(tq*4 + j)*NST];
      s = fmaf(__expf(dl*An), s, dl*bp*uu4[j]);
      sdl += dl;
    }
  }
  carryS[(size_t)(pair*NCHK + chunk)*16 + n] = s;
  if (n == 0) carryD[pair*NCHK + chunk] = sdl;
}

// ---------------- K4b: sequential carry combine across chunks ----------------
__launch_bounds__(256)
__global__ void k_scan2(const float* __restrict__ carryS, const float* __restrict__ carryD,
                        const float* __restrict__ Alog, float* __restrict__ xstart) {
  const int i = blockIdx.x * 256 + threadIdx.x;   // 0..24575: (pair, n)
  const int pair = i >> 4, n = i & 15;
  const int d = pair % DIN;
  const float An = -__expf(Alog[d*NST + n]);
  float x = 0.f;
  #pragma unroll
  for (int c = 0; c < NCHK; ++c) {
    xstart[(size_t)(pair*NCHK + c)*16 + n] = x;
    x = fmaf(__expf(An * carryD[pair*NCHK + c]), x, carryS[(size_t)(pair*NCHK + c)*16 + n]);
  }
}

// ---------------- K4c: chunked scan pass 2 — seeded recompute + y output ----------------
__launch_bounds__(256)
__global__ void k_scan3(const float* __restrict__ dgT, const float* __restrict__ ugT,
                        const float* __restrict__ Bg, const float* __restrict__ Cg,
                        const float* __restrict__ Alog, const float* __restrict__ Dp,
                        const float* __restrict__ xstart, unsigned short* __restrict__ yb) {
  const int tid  = threadIdx.x;
  const int n    = tid & 15;
  const int pair = blockIdx.x * 16 + (tid >> 4);
  const int chunk = blockIdx.y;
  const int b = pair / DIN, d = pair - b*DIN;
  const float An = -__expf(Alog[d*NST + n]);
  const float Dd = Dp[d];
  const float* dp  = dgT + ((size_t)(b*DIN + d))*LEN + chunk*TCH;
  const float* up  = ugT + ((size_t)(b*DIN + d))*LEN + chunk*TCH;
  const float* bp_ = Bg + ((size_t)b*LEN + chunk*TCH)*NST + n;
  const float* cp_ = Cg + ((size_t)b*LEN + chunk*TCH)*NST + n;
  unsigned short* yp = yb + ((size_t)b*LEN + chunk*TCH)*DIN + d;

  float s = xstart[(size_t)(pair*NCHK + chunk)*16 + n];
  #pragma unroll 2
  for (int tq = 0; tq < TCH/4; ++tq) {
    f32x4 dl4 = *(const f32x4*)(dp + tq*4);
    f32x4 uu4 = *(const f32x4*)(up + tq*4);
    #pragma unroll
    for (int j = 0; j < 4; ++j) {
      float dl = dl4[j];
      float bp = bp_[(size_t)(tq*4 + j)*NST];
      float cp = cp_[(size_t)(tq*4 + j)*NST];
      s = fmaf(__expf(dl*An), s, dl*bp*uu4[j]);
      float py = s * cp;
      py += __shfl_xor(py, 8);
      py += __shfl_xor(py, 4);
      py += __shfl_xor(py, 2);
      py += __shfl_xor(py, 1);
      if (n == 0) yp[(size_t)(tq*4 + j)*DIN] = f2bf(py + uu4[j]*Dd);
    }
  }
}

// ---------------- K5: out_proj (bf16 MFMA, swapped operands) + residual ----------------
// Y fragments read directly from global (L2-hot, 12.6MB); only W staged in LDS.
#define K6_MR 128
#define K6_NC 128
#define K6_LD 104   // 208B row stride = 13 x 16B granules (5 mod 8 -> 2-way max = free)

__launch_bounds__(256)
__global__ void k_outproj(const unsigned short* __restrict__ yb,
                          const unsigned short* __restrict__ Wb,  // (2048 x 96) bf16
                          const float* __restrict__ resid,
                          float* __restrict__ out) {
  __shared__ unsigned short W_lds[K6_NC][K6_LD];
  const int tid  = threadIdx.x;
  const int lane = tid & 63;
  const int w    = tid >> 6;
  const int r    = lane & 15;
  const int g    = lane >> 4;
  const int r0   = blockIdx.y * K6_MR;
  const int c0   = blockIdx.x * K6_NC;

  // stage W tile: 128 rows x 96 k = 12 granules/row = 1536 items = 6 x 256
  #pragma unroll
  for (int i = 0; i < 6; ++i) {
    int j = tid + 256*i;
    int row = j / 12, c8 = j - row*12;
    *(uint4*)&W_lds[row][c8*8] = *(const uint4*)(Wb + (size_t)(c0 + row)*DIN + c8*8);
  }
  __syncthreads();

  f32x4 acc[8][2];
  #pragma unroll
  for (int i = 0; i < 8; ++i)
    #pragma unroll
    for (int j = 0; j < 2; ++j) acc[i][j] = (f32x4){0.f, 0.f, 0.f, 0.f};

  const unsigned short* yrow0 = yb + (size_t)(r0 + w*32 + r)*DIN;
  #pragma unroll
  for (int kt = 0; kt < 3; ++kt) {     // K = 96 = 3 x 32
    const int krd = kt*32 + g*8;
    bf16x8 y0 = *(const bf16x8*)(yrow0 + krd);
    bf16x8 y1 = *(const bf16x8*)(yrow0 + 16*DIN + krd);
    #pragma unroll
    for (int ci = 0; ci < 8; ++ci) {
      bf16x8 wf = *(const bf16x8*)&W_lds[ci*16 + r][krd];
      acc[ci][0] = mfma16(wf, y0, acc[ci][0]);   // M-dim = out cols, N-dim = out rows
      acc[ci][1] = mfma16(wf, y1, acc[ci][1]);
    }
  }

  // epilogue: lane -> row (w*32 + ri*16 + r), cols ci*16 + g*4 + {0..3}: float4 RMW
  #pragma unroll
  for (int ci = 0; ci < 8; ++ci)
    #pragma unroll
    for (int ri = 0; ri < 2; ++ri) {
      size_t row = (size_t)(r0 + w*32 + ri*16 + r);
      size_t col = (size_t)(c0 + ci*16 + g*4);
      const float4 rv = *(const float4*)(resid + row*CH + col);
      f32x4 a = acc[ci][ri];
      float4 o = make_float4(a[0] + rv.x, a[1] + rv.y, a[2] + rv.z, a[3] + rv.w);
      *(float4*)(out + row*CH + col) = o;
    }
}

extern "C" void kernel_launch(void* const* d_in, const int* in_sizes, int n_in,
                              void* d_out, int out_size, void* d_ws, size_t ws_size,
                              hipStream_t stream) {
  const float* feat = (const float*)d_in[0];
  const float* lnw  = (const float*)d_in[1];
  const float* lnb  = (const float*)d_in[2];
  const float* inW  = (const float*)d_in[3];
  const float* cw   = (const float*)d_in[4];
  const float* cb   = (const float*)d_in[5];
  const float* xW   = (const float*)d_in[6];
  const float* dtW  = (const float*)d_in[7];
  const float* dtb  = (const float*)d_in[8];
  const float* Alog = (const float*)d_in[9];
  const float* Dp   = (const float*)d_in[10];
  const float* outW = (const float*)d_in[11];
  float* out = (float*)d_out;

  char* ws = (char*)d_ws;
  size_t off = 0;
  auto alloc = [&](size_t bytes) { void* p = ws + off; off += (bytes + 255) & ~255ull; return p; };
  unsigned short* inWb  = (unsigned short*)alloc((size_t)DIN*CH*2);
  unsigned short* outWb = (unsigned short*)alloc((size_t)CH*DIN*2);
  float* M1t = (float*)alloc((size_t)DIN*DIN*4);
  float* xBC = (float*)alloc((size_t)DIN*32*4);
  float* pvec = (float*)alloc((size_t)DIN*4);
  float* qvec = (float*)alloc((size_t)DIN*4);
  float* xin = (float*)alloc((size_t)NROW*DIN*4);
  float* ugT = (float*)alloc((size_t)NROW*DIN*4);
  float* dgT = (float*)alloc((size_t)NROW*DIN*4);
  float* Bg  = (float*)alloc((size_t)NROW*NST*4);
  float* Cg  = (float*)alloc((size_t)NROW*NST*4);
  unsigned short* yb = (unsigned short*)alloc((size_t)NROW*DIN*2);
  float* carryS = (float*)alloc((size_t)NPAIR*NCHK*NST*4);
  float* carryD = (float*)alloc((size_t)NPAIR*NCHK*4);
  float* xstart = (float*)alloc((size_t)NPAIR*NCHK*NST*4);

  hipLaunchKernelGGL(k_prep, dim3((DIN*CH + 255)/256), dim3(256), 0, stream,
                     inW, outW, xW, dtW, lnw, inWb, outWb, M1t, xBC);
  hipLaunchKernelGGL(k_prep2, dim3(DIN), dim3(256), 0, stream,
                     inW, lnw, lnb, pvec, qvec);
  hipLaunchKernelGGL(k_ln_inproj, dim3(NROW/64), dim3(256), 0, stream,
                     feat, inWb, pvec, qvec, xin);
  hipLaunchKernelGGL(k_conv_proj, dim3(LEN/K3_R, BSZ), dim3(128), 0, stream,
                     xin, cw, cb, xBC, M1t, dtb, ugT, dgT, Bg, Cg);
  hipLaunchKernelGGL(k_scan1, dim3(NPAIR/16, NCHK), dim3(256), 0, stream,
                     dgT, ugT, Bg, Alog, carryS, carryD);
  hipLaunchKernelGGL(k_scan2, dim3(NPAIR*NST/256), dim3(256), 0, stream,
                     carryS, carryD, Alog, xstart);
  hipLaunchKernelGGL(k_scan3, dim3(NPAIR/16, NCHK), dim3(256), 0, stream,
                     dgT, ugT, Bg, Cg, Alog, Dp, xstart, yb);
  hipLaunchKernelGGL(k_outproj, dim3(CH/K6_NC, NROW/K6_MR), dim3(256), 0, stream,
                     yb, outWb, feat, out);
}